// Round 3
// baseline (91.506 us; speedup 1.0000x reference)
//
#include <hip/hip_runtime.h>

// 4-level MoE routing loss, B=8, H=1024, ROUTE=64, 16x16 patches/level.
// d_in order: out0, gt0, out1, gt1, out2, gt2, out3, gt3   (all fp32)
// d_out (fp32, flat, return order):
//   [0]                  loss (1)
//   [1 .. 8388609)       label_patch (8,1,1024,1024)
//   [8388609 .. +2048)   moe_label (8,1,16,16) as float 0..3
//   [8390657 .. +8192)   score (8,4,16,16)
// ws: [0] u64 loss accumulator (fixed-point 2^54), [8] u32 ticket counter.
//
// R3: single fused kernel. Block p (= b*256 + patch) computes err/gt sums
// for its patch at all 4 levels, then score+argmin+moe, contributes its
// loss term via INTEGER atomicAdd (associative -> deterministic), and
// immediately assembles its own 64x64 label_patch tile (gt data is L1/L2
// hot from phase 1). Loss masked-MSE decomposes exactly into per-patch
// err sums: loss = sum_p [ E0/N0 + (m>=1)E1/N1 + (m>=2)E2/N2 + (m>=3)E3/N3 ].

#define NPATCH 2048
#define LOSS_SCALE 18014398509481984.0   // 2^54

__global__ __launch_bounds__(256) void fused_kernel(
    const float* __restrict__ out0, const float* __restrict__ gt0,
    const float* __restrict__ out1, const float* __restrict__ gt1,
    const float* __restrict__ out2, const float* __restrict__ gt2,
    const float* __restrict__ out3, const float* __restrict__ gt3,
    float* __restrict__ scoreOut,   // (B,4,16,16)
    float* __restrict__ moeF,       // moe_label as float
    float* __restrict__ lab,        // label_patch (8,1,1024,1024), base o+1
    float* __restrict__ lossOut,    // d_out[0]
    unsigned long long* __restrict__ lossAcc,
    unsigned int* __restrict__ ticket)
{
    const int p = blockIdx.x;          // b*256 + l
    const int b = p >> 8;
    const int l = p & 255;
    const int py = l >> 4, px = l & 15;

    const float* PO[4] = {out0, out1, out2, out3};
    const float* PG[4] = {gt0, gt1, gt2, gt3};

    float err[4], gts[4];

    #pragma unroll
    for (int lev = 0; lev < 4; ++lev) {
        const int k  = 64 >> lev;          // compile-time per unrolled iter
        const int W  = 1024 >> lev;
        const int kv = k >> 2;
        const int nvec = k * kv;
        const int rowBase = py * k, colBase = px * k;
        const size_t base = (size_t)b * W * W;
        const float* po = PO[lev];
        const float* pg = PG[lev];

        float e = 0.f, g = 0.f;
        for (int idx = threadIdx.x; idx < nvec; idx += 256) {
            int r = idx / kv;
            int c = (idx % kv) * 4;
            size_t off = base + (size_t)(rowBase + r) * W + (colBase + c);
            float4 o = *(const float4*)(po + off);
            float4 q = *(const float4*)(pg + off);
            float dx = o.x - q.x, dy = o.y - q.y, dz = o.z - q.z, dw = o.w - q.w;
            e += dx * dx + dy * dy + dz * dz + dw * dw;
            g += q.x + q.y + q.z + q.w;
        }
        err[lev] = e; gts[lev] = g;
    }

    for (int s = 32; s; s >>= 1) {
        #pragma unroll
        for (int i = 0; i < 4; ++i) {
            err[i] += __shfl_down(err[i], s, 64);
            gts[i] += __shfl_down(gts[i], s, 64);
        }
    }
    __shared__ float se[4][4], sg[4][4];
    __shared__ int sm;
    const int wave = threadIdx.x >> 6, lane = threadIdx.x & 63;
    if (lane == 0) {
        #pragma unroll
        for (int i = 0; i < 4; ++i) { se[i][wave] = err[i]; sg[i][wave] = gts[i]; }
    }
    __syncthreads();
    if (threadIdx.x == 0) {
        float E[4], S[4];
        #pragma unroll
        for (int i = 0; i < 4; ++i) {
            E[i] = se[i][0] + se[i][1] + se[i][2] + se[i][3];
            float G = sg[i][0] + sg[i][1] + sg[i][2] + sg[i][3];
            float kk = (float)((64 >> i) * (64 >> i));
            S[i] = E[i] / kk + E[i] / (G + 1e-10f);
            scoreOut[b * 1024 + i * 256 + l] = S[i];
        }
        int m = 0; float best = S[0];
        #pragma unroll
        for (int i = 1; i < 4; ++i)
            if (S[i] < best) { best = S[i]; m = i; }   // strict <, first-min
        moeF[p] = (float)m;
        sm = m;
        double t = (double)E[0] / 8388608.0;
        if (m >= 1) t += (double)E[1] / 2097152.0;
        if (m >= 2) t += (double)E[2] / 524288.0;
        if (m >= 3) t += (double)E[3] / 131072.0;
        unsigned long long fx = (unsigned long long)llrint(t * LOSS_SCALE);
        atomicAdd(lossAcc, fx);
        __threadfence();
        unsigned int tk = atomicAdd(ticket, 1u);
        if (tk == NPATCH - 1) {
            unsigned long long total = atomicAdd(lossAcc, 0ULL);  // coherent read
            lossOut[0] = (float)((double)total / LOSS_SCALE);
        }
    }
    __syncthreads();
    const int m = sm;

    // ---- phase 2: write this block's 64x64 label tile (scalar stores;
    //      lab base is d_out+1, only 4B-aligned) ----
    const size_t labBase = (size_t)b * 1048576 + (size_t)(py * 64) * 1024 + px * 64;
    if (m == 0) {
        for (int idx = threadIdx.x; idx < 4096; idx += 256) {
            int y = idx >> 6, x = idx & 63;
            size_t off = labBase + (size_t)y * 1024 + x;
            // gt0 pixel at same global coords:
            size_t goff = (size_t)b * 1048576 + (size_t)(py * 64 + y) * 1024 + (px * 64 + x);
            lab[off] = gt0[goff];
        }
    } else {
        const int k = 64 >> m, pad = (64 - k) >> 1, W = 1024 >> m;
        const float* gt = (m == 1) ? gt1 : (m == 2) ? gt2 : gt3;
        const size_t gbase = (size_t)b * W * W;
        for (int idx = threadIdx.x; idx < 4096; idx += 256) {
            int y = idx >> 6, x = idx & 63;
            int iy = y - pad, ix = x - pad;
            float v = 0.2f;
            if ((unsigned)iy < (unsigned)k && (unsigned)ix < (unsigned)k)
                v = gt[gbase + (size_t)(py * k + iy) * W + (px * k + ix)];
            lab[labBase + (size_t)y * 1024 + x] = v;
        }
    }
}

extern "C" void kernel_launch(void* const* d_in, const int* in_sizes, int n_in,
                              void* d_out, int out_size, void* d_ws, size_t ws_size,
                              hipStream_t stream) {
    const float* out0 = (const float*)d_in[0];
    const float* gt0  = (const float*)d_in[1];
    const float* out1 = (const float*)d_in[2];
    const float* gt1  = (const float*)d_in[3];
    const float* out2 = (const float*)d_in[4];
    const float* gt2  = (const float*)d_in[5];
    const float* out3 = (const float*)d_in[6];
    const float* gt3  = (const float*)d_in[7];

    float* o = (float*)d_out;
    float* lossOut  = o;
    float* labOut   = o + 1;
    float* moeFOut  = o + 8388609;
    float* scoreOut = o + 8390657;

    unsigned long long* lossAcc = (unsigned long long*)d_ws;
    unsigned int* ticket = (unsigned int*)((char*)d_ws + 8);

    hipMemsetAsync(d_ws, 0, 16, stream);   // zero acc + ticket (capturable)

    fused_kernel<<<NPATCH, 256, 0, stream>>>(
        out0, gt0, out1, gt1, out2, gt2, out3, gt3,
        scoreOut, moeFOut, labOut, lossOut, lossAcc, ticket);
}

// Round 4
// 54.259 us; speedup vs baseline: 1.6865x; 1.6865x over previous
//
#include <hip/hip_runtime.h>

// 4-level MoE routing loss, B=8, H=1024, ROUTE=64, 16x16 patches/level.
// d_in order: out0, gt0, out1, gt1, out2, gt2, out3, gt3   (all fp32)
// d_out (fp32, flat, return order):
//   [0]                  loss (1)
//   [1 .. 8388609)       label_patch (8,1,1024,1024)
//   [8388609 .. +2048)   moe_label (8,1,16,16) as float 0..3
//   [8390657 .. +8192)   score (8,4,16,16)
// ws: [0..8) u64 packed loss accumulator: bits 0..51 loss fixed-point
//     (scale 2^48), bits 52..63 block-arrival count. One atomicAdd per
//     block; the RMW whose returned old-count == NPATCH-1 holds the full
//     sum -> writes loss. Integer sum = associative = deterministic.
//     NO __threadfence (R3 post-mortem: device fence = buffer_wbl2 L2
//     writeback per block = 2.4x regression).
//
// Block p = b*256 + patch: phase 1 computes err/gt sums for all 4 levels
// (staging its 64x64 gt0 patch into LDS on the way), phase 2 assembles its
// own 64x64 label tile (m==0 from LDS; m>0 reads tiny L3-hot gt_m patch).

#define NPATCH 2048
#define LOSS_SCALE 281474976710656.0   // 2^48
#define CNT_ONE (1ULL << 52)

__global__ __launch_bounds__(256) void fused_kernel(
    const float* __restrict__ out0, const float* __restrict__ gt0,
    const float* __restrict__ out1, const float* __restrict__ gt1,
    const float* __restrict__ out2, const float* __restrict__ gt2,
    const float* __restrict__ out3, const float* __restrict__ gt3,
    float* __restrict__ scoreOut,   // (B,4,16,16)
    float* __restrict__ moeF,       // moe_label as float
    float* __restrict__ lab,        // label_patch base (d_out+1)
    float* __restrict__ lossOut,    // d_out[0]
    unsigned long long* __restrict__ lossAcc)
{
    __shared__ float tile0[64][64];     // this block's gt0 patch (16KB)
    __shared__ float se[4][4], sg[4][4];
    __shared__ int sm;

    const int p = blockIdx.x;          // b*256 + l
    const int b = p >> 8;
    const int l = p & 255;
    const int py = l >> 4, px = l & 15;

    const float* PO[4] = {out0, out1, out2, out3};
    const float* PG[4] = {gt0, gt1, gt2, gt3};

    float err[4], gts[4];

    #pragma unroll
    for (int lev = 0; lev < 4; ++lev) {
        const int k  = 64 >> lev;          // compile-time per unrolled iter
        const int W  = 1024 >> lev;
        const int kv = k >> 2;
        const int nvec = k * kv;
        const int rowBase = py * k, colBase = px * k;
        const size_t base = (size_t)b * W * W;
        const float* po = PO[lev];
        const float* pg = PG[lev];

        float e = 0.f, g = 0.f;
        for (int idx = threadIdx.x; idx < nvec; idx += 256) {
            int r = idx / kv;
            int c = (idx % kv) * 4;
            size_t off = base + (size_t)(rowBase + r) * W + (colBase + c);
            float4 o = *(const float4*)(po + off);
            float4 q = *(const float4*)(pg + off);
            float dx = o.x - q.x, dy = o.y - q.y, dz = o.z - q.z, dw = o.w - q.w;
            e += dx * dx + dy * dy + dz * dz + dw * dw;
            g += q.x + q.y + q.z + q.w;
            if (lev == 0) *(float4*)&tile0[r][c] = q;   // stage gt0 in LDS
        }
        err[lev] = e; gts[lev] = g;
    }

    for (int s = 32; s; s >>= 1) {
        #pragma unroll
        for (int i = 0; i < 4; ++i) {
            err[i] += __shfl_down(err[i], s, 64);
            gts[i] += __shfl_down(gts[i], s, 64);
        }
    }
    const int wave = threadIdx.x >> 6, lane = threadIdx.x & 63;
    if (lane == 0) {
        #pragma unroll
        for (int i = 0; i < 4; ++i) { se[i][wave] = err[i]; sg[i][wave] = gts[i]; }
    }
    __syncthreads();
    if (threadIdx.x == 0) {
        float E[4], S[4];
        #pragma unroll
        for (int i = 0; i < 4; ++i) {
            E[i] = se[i][0] + se[i][1] + se[i][2] + se[i][3];
            float G = sg[i][0] + sg[i][1] + sg[i][2] + sg[i][3];
            float kk = (float)((64 >> i) * (64 >> i));
            S[i] = E[i] / kk + E[i] / (G + 1e-10f);
            scoreOut[b * 1024 + i * 256 + l] = S[i];
        }
        int m = 0; float best = S[0];
        #pragma unroll
        for (int i = 1; i < 4; ++i)
            if (S[i] < best) { best = S[i]; m = i; }   // strict <, first-min
        moeF[p] = (float)m;
        sm = m;
        double t = (double)E[0] / 8388608.0;
        if (m >= 1) t += (double)E[1] / 2097152.0;
        if (m >= 2) t += (double)E[2] / 524288.0;
        if (m >= 3) t += (double)E[3] / 131072.0;
        unsigned long long fx =
            (unsigned long long)llrint(t * LOSS_SCALE) + CNT_ONE;
        unsigned long long old = atomicAdd(lossAcc, fx);
        if ((old >> 52) == NPATCH - 1) {               // I'm the last arrival
            unsigned long long total = old + fx;
            lossOut[0] = (float)((double)(total & (CNT_ONE - 1)) / LOSS_SCALE);
        }
    }
    __syncthreads();
    const int m = sm;

    // ---- phase 2: write this block's 64x64 label tile (scalar dword
    //      stores; lab base d_out+1 is only 4B-aligned). Each wave writes
    //      256B-contiguous row segments -> coalesced. ----
    const size_t labBase = (size_t)b * 1048576 + (size_t)(py * 64) * 1024 + px * 64;
    if (m == 0) {
        for (int idx = threadIdx.x; idx < 4096; idx += 256) {
            int y = idx >> 6, x = idx & 63;
            lab[labBase + (size_t)y * 1024 + x] = tile0[y][x];
        }
    } else {
        const int k = 64 >> m, pad = (64 - k) >> 1, W = 1024 >> m;
        const float* gt = (m == 1) ? gt1 : (m == 2) ? gt2 : gt3;
        const size_t gbase = (size_t)b * W * W;
        for (int idx = threadIdx.x; idx < 4096; idx += 256) {
            int y = idx >> 6, x = idx & 63;
            int iy = y - pad, ix = x - pad;
            float v = 0.2f;
            if ((unsigned)iy < (unsigned)k && (unsigned)ix < (unsigned)k)
                v = gt[gbase + (size_t)(py * k + iy) * W + (px * k + ix)];
            lab[labBase + (size_t)y * 1024 + x] = v;
        }
    }
}

extern "C" void kernel_launch(void* const* d_in, const int* in_sizes, int n_in,
                              void* d_out, int out_size, void* d_ws, size_t ws_size,
                              hipStream_t stream) {
    const float* out0 = (const float*)d_in[0];
    const float* gt0  = (const float*)d_in[1];
    const float* out1 = (const float*)d_in[2];
    const float* gt1  = (const float*)d_in[3];
    const float* out2 = (const float*)d_in[4];
    const float* gt2  = (const float*)d_in[5];
    const float* out3 = (const float*)d_in[6];
    const float* gt3  = (const float*)d_in[7];

    float* o = (float*)d_out;
    float* lossOut  = o;
    float* labOut   = o + 1;
    float* moeFOut  = o + 8388609;
    float* scoreOut = o + 8390657;

    unsigned long long* lossAcc = (unsigned long long*)d_ws;

    hipMemsetAsync(d_ws, 0, 8, stream);   // zero packed accumulator

    fused_kernel<<<NPATCH, 256, 0, stream>>>(
        out0, gt0, out1, gt1, out2, gt2, out3, gt3,
        scoreOut, moeFOut, labOut, lossOut, lossAcc);
}

// Round 5
// 46.076 us; speedup vs baseline: 1.9860x; 1.1776x over previous
//
#include <hip/hip_runtime.h>

// 4-level MoE routing loss, B=8, H=1024, ROUTE=64, 16x16 patches/level.
// d_in: out0, gt0, out1, gt1, out2, gt2, out3, gt3   (all fp32)
// d_out (fp32 flat): [0] loss | [1..8388609) label_patch (8,1024,1024)
//   | [+2048) moe_label as float | [+8192) score (8,4,16,16)
// ws: u64 acc[4][2048][2] fixed-point (2^44) err/gt sums @0 (128KB, zeroed
//     per call via memsetAsync); double lossTerm[2048] @131072.
//
// R5 structure (R3/R4 fusion falsified — contended returning atomics):
//  K1 sum_kernel: PURE LINEAR streaming of all images, 1 float4/thread,
//     aligned lane-group reduce (16/8/4/2 lanes = one patch-row segment),
//     fire-and-forget u64 atomicAdd into per-patch accumulators.
//     Integer adds are associative -> bit-deterministic.
//  K2 finalize_kernel: block p reads its 8 accumulators, every thread
//     redundantly computes score/argmin (no LDS, no barriers); thread 0
//     writes score/moe/lossTerm; all threads write the 64x64 label tile.
//  K3 loss_kernel: single block, fixed-order reduce of 2048 lossTerms.

#define SCALE 17592186044416.0   // 2^44
#define NPATCH 2048

__global__ __launch_bounds__(256) void sum_kernel(
    const float* __restrict__ out0, const float* __restrict__ gt0,
    const float* __restrict__ out1, const float* __restrict__ gt1,
    const float* __restrict__ out2, const float* __restrict__ gt2,
    const float* __restrict__ out3, const float* __restrict__ gt3,
    unsigned long long* __restrict__ acc)
{
    const int blk = blockIdx.x;
    const int t = threadIdx.x;
    const float* po; const float* pg;
    int lev, b, row, x4, W4, py, pcol, grp;
    if (blk < 8192) {            // level 0: 1 row (1024px) per block
        lev = 0; b = blk >> 10; row = blk & 1023;
        x4 = t; W4 = 256; py = row >> 6; pcol = t >> 4; grp = 16;
        po = out0; pg = gt0;
    } else if (blk < 10240) {    // level 1: 2 rows (512px) per block
        int z = blk - 8192; lev = 1; b = z >> 8; int j = z & 255;
        row = 2 * j + (t >> 7); x4 = t & 127; W4 = 128;
        py = row >> 5; pcol = x4 >> 3; grp = 8;
        po = out1; pg = gt1;
    } else if (blk < 10752) {    // level 2: 4 rows (256px) per block
        int z = blk - 10240; lev = 2; b = z >> 6; int j = z & 63;
        row = 4 * j + (t >> 6); x4 = t & 63; W4 = 64;
        py = row >> 4; pcol = x4 >> 2; grp = 4;
        po = out2; pg = gt2;
    } else {                     // level 3: 8 rows (128px) per block
        int z = blk - 10752; lev = 3; b = z >> 4; int j = z & 15;
        row = 8 * j + (t >> 5); x4 = t & 31; W4 = 32;
        py = row >> 3; pcol = x4 >> 1; grp = 2;
        po = out3; pg = gt3;
    }
    const int nrows = W4 << 2;
    const size_t idx = ((size_t)b * nrows + row) * W4 + x4;

    float4 o = ((const float4*)po)[idx];
    float4 q = ((const float4*)pg)[idx];
    float dx = o.x - q.x, dy = o.y - q.y, dz = o.z - q.z, dw = o.w - q.w;
    float e = dx * dx + dy * dy + dz * dz + dw * dw;
    float g = q.x + q.y + q.z + q.w;

    // reduce within aligned lane-group of size grp (one patch-row segment)
    for (int s = grp >> 1; s; s >>= 1) {
        e += __shfl_down(e, s, grp);
        g += __shfl_down(g, s, grp);
    }
    if ((t & (grp - 1)) == 0) {
        const int ai = (((lev << 11) | (b << 8) | (py << 4) | pcol) << 1);
        atomicAdd(&acc[ai],     (unsigned long long)llrint((double)e * SCALE));
        atomicAdd(&acc[ai + 1], (unsigned long long)llrint((double)g * SCALE));
    }
}

__global__ __launch_bounds__(256) void finalize_kernel(
    const float* __restrict__ gt0, const float* __restrict__ gt1,
    const float* __restrict__ gt2, const float* __restrict__ gt3,
    const unsigned long long* __restrict__ acc,
    float* __restrict__ scoreOut, float* __restrict__ moeF,
    float* __restrict__ lab, double* __restrict__ lossTerm)
{
    const int p = blockIdx.x;          // b*256 + l
    const int b = p >> 8;
    const int l = p & 255;
    const int py = l >> 4, px = l & 15;

    float E[4], S[4];
    #pragma unroll
    for (int i = 0; i < 4; ++i) {
        const int ai = (((i << 11) | p) << 1);
        double e = (double)acc[ai] / SCALE;
        double g = (double)acc[ai + 1] / SCALE;
        E[i] = (float)e;
        float kk = (float)((64 >> i) * (64 >> i));
        S[i] = E[i] / kk + E[i] / ((float)g + 1e-10f);
    }
    int m = 0; float best = S[0];
    #pragma unroll
    for (int i = 1; i < 4; ++i)
        if (S[i] < best) { best = S[i]; m = i; }   // strict < : first-min

    if (threadIdx.x == 0) {
        #pragma unroll
        for (int i = 0; i < 4; ++i)
            scoreOut[b * 1024 + i * 256 + l] = S[i];
        moeF[p] = (float)m;
        double t = (double)E[0] / 8388608.0;
        if (m >= 1) t += (double)E[1] / 2097152.0;
        if (m >= 2) t += (double)E[2] / 524288.0;
        if (m >= 3) t += (double)E[3] / 131072.0;
        lossTerm[p] = t;
    }

    // label tile (scalar dword stores; lab base d_out+1 is 4B-aligned only)
    const size_t labBase = (size_t)b * 1048576 + (size_t)(py * 64) * 1024 + px * 64;
    if (m == 0) {
        for (int idx = threadIdx.x; idx < 4096; idx += 256) {
            int y = idx >> 6, x = idx & 63;
            size_t goff = (size_t)b * 1048576 + (size_t)(py * 64 + y) * 1024 + (px * 64 + x);
            lab[labBase + (size_t)y * 1024 + x] = gt0[goff];
        }
    } else {
        const int k = 64 >> m, pad = (64 - k) >> 1, W = 1024 >> m;
        const float* gt = (m == 1) ? gt1 : (m == 2) ? gt2 : gt3;
        const size_t gbase = (size_t)b * W * W;
        for (int idx = threadIdx.x; idx < 4096; idx += 256) {
            int y = idx >> 6, x = idx & 63;
            int iy = y - pad, ix = x - pad;
            float v = 0.2f;
            if ((unsigned)iy < (unsigned)k && (unsigned)ix < (unsigned)k)
                v = gt[gbase + (size_t)(py * k + iy) * W + (px * k + ix)];
            lab[labBase + (size_t)y * 1024 + x] = v;
        }
    }
}

__global__ __launch_bounds__(256) void loss_kernel(
    const double* __restrict__ lossTerm, float* __restrict__ lossOut)
{
    double t = 0.0;
    for (int i = threadIdx.x; i < NPATCH; i += 256) t += lossTerm[i];
    for (int s = 32; s; s >>= 1) t += __shfl_down(t, s, 64);
    __shared__ double sd[4];
    const int wave = threadIdx.x >> 6, lane = threadIdx.x & 63;
    if (lane == 0) sd[wave] = t;
    __syncthreads();
    if (threadIdx.x == 0)
        lossOut[0] = (float)(sd[0] + sd[1] + sd[2] + sd[3]);
}

extern "C" void kernel_launch(void* const* d_in, const int* in_sizes, int n_in,
                              void* d_out, int out_size, void* d_ws, size_t ws_size,
                              hipStream_t stream) {
    const float* out0 = (const float*)d_in[0];
    const float* gt0  = (const float*)d_in[1];
    const float* out1 = (const float*)d_in[2];
    const float* gt1  = (const float*)d_in[3];
    const float* out2 = (const float*)d_in[4];
    const float* gt2  = (const float*)d_in[5];
    const float* out3 = (const float*)d_in[6];
    const float* gt3  = (const float*)d_in[7];

    float* o = (float*)d_out;
    float* lossOut  = o;
    float* labOut   = o + 1;
    float* moeFOut  = o + 8388609;
    float* scoreOut = o + 8390657;

    unsigned long long* acc = (unsigned long long*)d_ws;
    double* lossTerm = (double*)((char*)d_ws + 131072);

    hipMemsetAsync(d_ws, 0, 131072, stream);   // zero accumulators each call

    sum_kernel<<<10880, 256, 0, stream>>>(
        out0, gt0, out1, gt1, out2, gt2, out3, gt3, acc);
    finalize_kernel<<<NPATCH, 256, 0, stream>>>(
        gt0, gt1, gt2, gt3, acc, scoreOut, moeFOut, labOut, lossTerm);
    loss_kernel<<<1, 256, 0, stream>>>(lossTerm, lossOut);
}

// Round 6
// 30.830 us; speedup vs baseline: 2.9681x; 1.4945x over previous
//
#include <hip/hip_runtime.h>

// 4-level MoE routing loss, B=8, H=1024, ROUTE=64, 16x16 patches/level.
// d_in: out0, gt0, out1, gt1, out2, gt2, out3, gt3   (all fp32)
// d_out (fp32 flat): [0] loss | [1..8388609) label_patch (8,1024,1024)
//   | [+2048) moe_label as float | [+8192) score (8,4,16,16)
// ws: double lossTerm[2048] @0 (16KB). No atomics, no memset needed.
//
// R6: fused per-patch kernel, NO atomics/fences (R4 suspect #1 removed),
// NO LDS image staging (suspect #2 removed). Block p = b*256+patch:
//   phase 1: err/gt sums for all 4 levels -> score, argmin (patch-local!),
//            moe, lossTerm[p] (ws).
//   phase 2: write own 64x64 label tile; stores vectorized as
//            3 scalar + 15 dwordx4 + 1 scalar per row (d_out+1 is 4B-aligned
//            so quads live at lab indices 3+4j..6+4j; a quad never crosses a
//            patch boundary since the tile row is patch-local).
// K2: 1-block fixed-order reduce of 2048 lossTerms (deterministic).

#define NPATCH 2048

__global__ __launch_bounds__(256) void fused_kernel(
    const float* __restrict__ out0, const float* __restrict__ gt0,
    const float* __restrict__ out1, const float* __restrict__ gt1,
    const float* __restrict__ out2, const float* __restrict__ gt2,
    const float* __restrict__ out3, const float* __restrict__ gt3,
    float* __restrict__ scoreOut,   // (B,4,16,16)
    float* __restrict__ moeF,       // moe_label as float
    float* __restrict__ lab,        // label_patch base (d_out+1)
    double* __restrict__ lossTerm)  // ws [2048]
{
    const int p = blockIdx.x;          // b*256 + l
    const int b = p >> 8;
    const int l = p & 255;
    const int py = l >> 4, px = l & 15;

    const float* PO[4] = {out0, out1, out2, out3};
    const float* PG[4] = {gt0, gt1, gt2, gt3};

    float err[4], gts[4];

    #pragma unroll
    for (int lev = 0; lev < 4; ++lev) {
        const int k  = 64 >> lev;          // compile-time per unrolled iter
        const int W  = 1024 >> lev;
        const int kv = k >> 2;
        const int nvec = k * kv;
        const int rowBase = py * k, colBase = px * k;
        const size_t base = (size_t)b * W * W;
        const float* po = PO[lev];
        const float* pg = PG[lev];

        float e = 0.f, g = 0.f;
        for (int idx = threadIdx.x; idx < nvec; idx += 256) {
            int r = idx / kv;
            int c = (idx % kv) * 4;
            size_t off = base + (size_t)(rowBase + r) * W + (colBase + c);
            float4 o = *(const float4*)(po + off);
            float4 q = *(const float4*)(pg + off);
            float dx = o.x - q.x, dy = o.y - q.y, dz = o.z - q.z, dw = o.w - q.w;
            e += dx * dx + dy * dy + dz * dz + dw * dw;
            g += q.x + q.y + q.z + q.w;
        }
        err[lev] = e; gts[lev] = g;
    }

    for (int s = 32; s; s >>= 1) {
        #pragma unroll
        for (int i = 0; i < 4; ++i) {
            err[i] += __shfl_down(err[i], s, 64);
            gts[i] += __shfl_down(gts[i], s, 64);
        }
    }
    __shared__ float se[4][4], sg[4][4];
    __shared__ int sm;
    const int wave = threadIdx.x >> 6, lane = threadIdx.x & 63;
    if (lane == 0) {
        #pragma unroll
        for (int i = 0; i < 4; ++i) { se[i][wave] = err[i]; sg[i][wave] = gts[i]; }
    }
    __syncthreads();
    if (threadIdx.x == 0) {
        float E[4], S[4];
        #pragma unroll
        for (int i = 0; i < 4; ++i) {
            E[i] = se[i][0] + se[i][1] + se[i][2] + se[i][3];
            float G = sg[i][0] + sg[i][1] + sg[i][2] + sg[i][3];
            float kk = (float)((64 >> i) * (64 >> i));
            S[i] = E[i] / kk + E[i] / (G + 1e-10f);
            scoreOut[b * 1024 + i * 256 + l] = S[i];
        }
        int m = 0; float best = S[0];
        #pragma unroll
        for (int i = 1; i < 4; ++i)
            if (S[i] < best) { best = S[i]; m = i; }   // strict <, first-min
        moeF[p] = (float)m;
        sm = m;
        double t = (double)E[0] / 8388608.0;
        if (m >= 1) t += (double)E[1] / 2097152.0;
        if (m >= 2) t += (double)E[2] / 524288.0;
        if (m >= 3) t += (double)E[3] / 131072.0;
        lossTerm[p] = t;
    }
    __syncthreads();
    const int m = sm;

    // ---- phase 2: write own 64x64 label tile, vectorized stores ----
    // lab-coord of tile row y starts at R0 = labBase + y*1024 (R0 % 4 == 0).
    // d_out index = lab index + 1, so aligned float4 slots are lab[3+4j..6+4j].
    // Work item idx (0..1023): y = idx>>4, j = idx&15; j<15 -> quad j,
    // j==15 -> row's 4 scalar remainders (lab R0+0..2 and R0+63).
    const size_t labBase = (size_t)b * 1048576 + (size_t)(py * 64) * 1024 + px * 64;

    if (m == 0) {
        // tile == gt0 tile (same global coordinates as labBase)
        for (int idx = threadIdx.x; idx < 1024; idx += 256) {
            int y = idx >> 4, j = idx & 15;
            size_t R0 = labBase + (size_t)y * 1024;
            if (j < 15) {
                int x = 3 + 4 * j;
                float4 v;
                v.x = gt0[R0 + x];
                v.y = gt0[R0 + x + 1];
                v.z = gt0[R0 + x + 2];
                v.w = gt0[R0 + x + 3];
                *(float4*)(lab + R0 + x) = v;
            } else {
                lab[R0]     = gt0[R0];
                lab[R0 + 1] = gt0[R0 + 1];
                lab[R0 + 2] = gt0[R0 + 2];
                lab[R0 + 63] = gt0[R0 + 63];
            }
        }
    } else {
        const int k = 64 >> m, pad = (64 - k) >> 1, W = 1024 >> m;
        const float* gt = (m == 1) ? gt1 : (m == 2) ? gt2 : gt3;
        const size_t gbase = (size_t)b * W * W + (size_t)(py * k) * W + px * k;
        for (int idx = threadIdx.x; idx < 1024; idx += 256) {
            int y = idx >> 4, j = idx & 15;
            size_t R0 = labBase + (size_t)y * 1024;
            int iy = y - pad;
            bool rowIn = (unsigned)iy < (unsigned)k;
            const float* grow = gt + gbase + (size_t)iy * W;
            if (j < 15) {
                int x = 3 + 4 * j;
                float4 v;
                #pragma unroll
                for (int u = 0; u < 4; ++u) {
                    int ix = x + u - pad;
                    float vv = 0.2f;
                    if (rowIn && (unsigned)ix < (unsigned)k) vv = grow[ix];
                    ((float*)&v)[u] = vv;
                }
                *(float4*)(lab + R0 + x) = v;
            } else {
                #pragma unroll
                for (int u = 0; u < 3; ++u) {
                    int ix = u - pad;
                    float vv = 0.2f;
                    if (rowIn && (unsigned)ix < (unsigned)k) vv = grow[ix];
                    lab[R0 + u] = vv;
                }
                int ix = 63 - pad;
                float vv = 0.2f;
                if (rowIn && (unsigned)ix < (unsigned)k) vv = grow[ix];
                lab[R0 + 63] = vv;
            }
        }
    }
}

__global__ __launch_bounds__(256) void loss_kernel(
    const double* __restrict__ lossTerm, float* __restrict__ lossOut)
{
    double t = 0.0;
    for (int i = threadIdx.x; i < NPATCH; i += 256) t += lossTerm[i];
    for (int s = 32; s; s >>= 1) t += __shfl_down(t, s, 64);
    __shared__ double sd[4];
    const int wave = threadIdx.x >> 6, lane = threadIdx.x & 63;
    if (lane == 0) sd[wave] = t;
    __syncthreads();
    if (threadIdx.x == 0)
        lossOut[0] = (float)(sd[0] + sd[1] + sd[2] + sd[3]);
}

extern "C" void kernel_launch(void* const* d_in, const int* in_sizes, int n_in,
                              void* d_out, int out_size, void* d_ws, size_t ws_size,
                              hipStream_t stream) {
    const float* out0 = (const float*)d_in[0];
    const float* gt0  = (const float*)d_in[1];
    const float* out1 = (const float*)d_in[2];
    const float* gt1  = (const float*)d_in[3];
    const float* out2 = (const float*)d_in[4];
    const float* gt2  = (const float*)d_in[5];
    const float* out3 = (const float*)d_in[6];
    const float* gt3  = (const float*)d_in[7];

    float* o = (float*)d_out;
    float* lossOut  = o;
    float* labOut   = o + 1;
    float* moeFOut  = o + 8388609;
    float* scoreOut = o + 8390657;

    double* lossTerm = (double*)d_ws;

    fused_kernel<<<NPATCH, 256, 0, stream>>>(
        out0, gt0, out1, gt1, out2, gt2, out3, gt3,
        scoreOut, moeFOut, labOut, lossTerm);
    loss_kernel<<<1, 256, 0, stream>>>(lossTerm, lossOut);
}